// Round 4
// baseline (330.379 us; speedup 1.0000x reference)
//
#include <hip/hip_runtime.h>

#define T_STEPS 2000
#define BATCH   2048

typedef float v2f __attribute__((ext_vector_type(2)));

// ---------------------------------------------------------------------------
// Pass 1: X[t][c] = (sum_k a[k] * c[t-63+k][c] - b_act) / max_current
// 256-thread blocks, CTT=16 rows/tile: 125x8 = 1000 blocks (~4/CU) hides
// load latency; refetch (16+63)/16 = 4.9x of 16 MB ~= 78 MB read -> ~15 us.
// ---------------------------------------------------------------------------
#define CTT 16
__global__ __launch_bounds__(256) void conv_kernel(
    const float* __restrict__ currents, const float* __restrict__ a,
    const float* __restrict__ b_act, const float* __restrict__ max_current,
    float* __restrict__ X)
{
    int tid = threadIdx.x;
    int t0  = blockIdx.x * CTT;              // 125 t-tiles, exact (2000/16)
    int c   = blockIdx.y * 256 + tid;        // 8 col-tiles

    float inv = 1.0f / max_current[0];
    float cb  = -b_act[0] * inv;

    float cur[CTT + 63];
#pragma unroll
    for (int rr = 0; rr < CTT + 63; ++rr) {
        int r = t0 - 63 + rr;                // max r = t0+15 <= 1999
        cur[rr] = (r >= 0) ? currents[(long)r * BATCH + c] : 0.0f;
    }
#pragma unroll
    for (int i = 0; i < CTT; ++i) {
        float acc = 0.0f;
#pragma unroll
        for (int k = 0; k < 64; ++k)
            acc = fmaf(a[k], cur[i + k], acc);   // a[k]: scalar (s_load) operand
        X[(long)(t0 + i) * BATCH + c] = fmaf(acc, inv, cb);
    }
}

// ---------------------------------------------------------------------------
// Pass 2: serial recurrence, ring fully IN-LANE. 1 lane = 1 column.
// Per lane: 64 ring regs; ring slot r (completing at phase r mod 64) is born
// with X[t_complete] and accumulates tapv[d-1]*f for each step d before
// completion. tapv[m] = (1000/mc)*b_lag[63-m]. Per step (phase phi):
//   u = ring[phi];  f = relu(M*tanh(poly(u)));  store f;
//   ring[phi] = X[t+64] (rebirth);  ring[(phi+d)&63] += tapv[d-1]*f, d=1..64
// as 32 v_pk_fma_f32. Pair alignment alternates with phi parity -> two tap
// copies TA (even-aligned) / TB (odd-aligned). Zero cross-lane ops.
//
// __launch_bounds__(64, 1): 1 wave/EU -> 512-VGPR budget. Round-3 lesson:
// without it the allocator capped at 188 < the 192-VGPR array footprint and
// spilled taps into the serial chain (274 cyc/step, VALUBusy 2.2%).
// ---------------------------------------------------------------------------
__global__ __launch_bounds__(64, 1) void rec_kernel(
    const float* X,                       // == out (scratch from pass 1)
    const float* __restrict__ b_lag, const float* __restrict__ poly_coeff,
    const float* __restrict__ max_current, const float* __restrict__ max_firing_rate,
    float* out)
{
    int lane = threadIdx.x;
    long col = (long)blockIdx.x * 64 + lane;

    float inv = 1.0f / max_current[0];
    float g   = 1000.0f * inv;

    v2f TA[32], TB[32];
#pragma unroll
    for (int j = 0; j < 32; ++j) {
        // tv[m] = g * b_lag[63 - m]
        TA[j] = (v2f){ g * b_lag[63 - 2*j], g * b_lag[62 - 2*j] };
        int m1 = (2*j + 1) & 63, m2i = (2*j + 2) & 63;
        TB[j] = (v2f){ g * b_lag[63 - m1], g * b_lag[63 - m2i] };
    }

    // tanh(p) = 1 - 2/(exp2(K2*p)+1); K2 = 2*log2(e) folded into squared coeffs.
    const float K2 = 2.8853900817779268f;
    float c0 = poly_coeff[0], c1 = poly_coeff[1], c2 = poly_coeff[2], c3 = poly_coeff[3];
    float k0 = K2*c0*c0, k1 = K2*c1*c1, k2 = K2*c2*c2, k3 = K2*c3*c3;
    float M  = max_firing_rate[0];
    float m2 = -2.0f * M;

    auto act = [&](float u) -> float {
        float u2 = u * u;                       // Estrin, depth 2
        float a1 = fmaf(u, k1, k0);
        float a2 = fmaf(u, k3, k2);
        float p  = fmaf(u2, a2, a1);
        float e  = __builtin_amdgcn_exp2f(p);
        float r_ = __builtin_amdgcn_rcpf(e + 1.0f);
        return fmaxf(fmaf(m2, r_, M), 0.0f);    // relu(M*tanh), overflow-free
    };

    v2f R[32];
#pragma unroll
    for (int r = 0; r < 64; ++r)                // slots for steps 0..63: born = X_t
        R[r >> 1][r & 1] = X[(long)r * BATCH + col];

    float xc[8], xn[8];
#pragma unroll
    for (int i = 0; i < 8; ++i)                 // future-X for phases 0..7 of chunk 0
        xc[i] = X[(long)(64 + i) * BATCH + col];

    // One step at compile-time phase phi. Critical-pair-first: the pair holding
    // slot phi+1 (the next step's u) is updated first so the next activation
    // chain overlaps the remaining 31 independent pk-FMAs.
    auto dostep = [&](int phi, float xreb, long t) {
        float u = R[phi >> 1][phi & 1];
        float f = act(u);
        out[t * BATCH + col] = f;
        R[phi >> 1][phi & 1] = xreb;            // rebirth: X[t+64]
        v2f ff = (v2f){ f, f };
        const int kc = (((phi + 1) & 63) >> 1); // pair containing slot phi+1
        if (phi & 1) {
            const int off = ((phi + 1) >> 1) & 31;  // TA[(k - off) & 31]
#pragma unroll
            for (int kk = 0; kk < 32; ++kk) {
                int k = (kc + kk) & 31;
                R[k] = __builtin_elementwise_fma(TA[(k - off) & 31], ff, R[k]);
            }
        } else {
            const int off = (1 + (phi >> 1)) & 31;  // TB[(k - off) & 31]
#pragma unroll
            for (int kk = 0; kk < 32; ++kk) {
                int k = (kc + kk) & 31;
                R[k] = __builtin_elementwise_fma(TB[(k - off) & 31], ff, R[k]);
            }
        }
    };

    for (int ch = 0; ch < 31; ++ch) {           // 31 full chunks: t = 0..1983
        long t0 = (long)ch * 64;
#pragma unroll
        for (int gph = 0; gph < 8; ++gph) {
            // prefetch next group's future-X (consumed 8 steps from now)
            long tf = t0 + 64 + (long)(gph + 1) * 8;
            if (tf + 7 < T_STEPS) {
#pragma unroll
                for (int i = 0; i < 8; ++i) xn[i] = X[(tf + i) * BATCH + col];
            } else {
#pragma unroll
                for (int i = 0; i < 8; ++i)
                    xn[i] = (tf + i < T_STEPS) ? X[(tf + i) * BATCH + col] : 0.0f;
            }
#pragma unroll
            for (int i = 0; i < 8; ++i)
                dostep(gph * 8 + i, xc[i], t0 + gph * 8 + i);
#pragma unroll
            for (int i = 0; i < 8; ++i) xc[i] = xn[i];  // rotate prefetch buffer
        }
    }

    // tail: 16 steps, t = 1984..1999 (rebirth value irrelevant; slots unused)
#pragma unroll
    for (int phi = 0; phi < 16; ++phi)
        dostep(phi, 0.0f, (long)(1984 + phi));
}

extern "C" void kernel_launch(void* const* d_in, const int* in_sizes, int n_in,
                              void* d_out, int out_size, void* d_ws, size_t ws_size,
                              hipStream_t stream) {
    const float* currents   = (const float*)d_in[0];
    const float* a          = (const float*)d_in[1];
    const float* b_lag      = (const float*)d_in[2];
    const float* poly_coeff = (const float*)d_in[3];
    const float* b_act      = (const float*)d_in[4];
    const float* mc         = (const float*)d_in[5];
    const float* mfr        = (const float*)d_in[6];
    float* out = (float*)d_out;

    // Pass 1: conv + bias + 1/mc folded -> X, staged in `out`.
    conv_kernel<<<dim3(T_STEPS / CTT, BATCH / 256), 256, 0, stream>>>(
        currents, a, b_act, mc, out);
    // Pass 2: in-lane serial recurrence, 64 columns/wave, 32 single-wave blocks.
    rec_kernel<<<BATCH / 64, 64, 0, stream>>>(out, b_lag, poly_coeff, mc, mfr, out);
}

// Round 5
// 267.368 us; speedup vs baseline: 1.2357x; 1.2357x over previous
//
#include <hip/hip_runtime.h>

#define T_STEPS 2000
#define BATCH   2048

typedef float v2f __attribute__((ext_vector_type(2)));

// DPP helper (ctrl = compile-time imm). quad_perm(a,b,c,d): ctrl = a|b<<2|c<<4|d<<6.
// 0xF5 = (1,1,3,3): lane 2c <- lane 2c+1 (partner pull for even lanes)
// 0xA0 = (0,0,2,2): lane 2c -> lanes 2c,2c+1 (pair broadcast from even lane)
template<int CTRL>
__device__ __forceinline__ float dppf(float v) {
    int i = __builtin_bit_cast(int, v);
    return __builtin_bit_cast(float,
        __builtin_amdgcn_update_dpp(i, i, CTRL, 0xf, 0xf, true));
}

// ---------------------------------------------------------------------------
// Pass 1: X[t][c] = (sum_k a[k] * c[t-63+k][c] - b_act) / max_current
// (unchanged from round 4)
// ---------------------------------------------------------------------------
#define CTT 16
__global__ __launch_bounds__(256) void conv_kernel(
    const float* __restrict__ currents, const float* __restrict__ a,
    const float* __restrict__ b_act, const float* __restrict__ max_current,
    float* __restrict__ X)
{
    int tid = threadIdx.x;
    int t0  = blockIdx.x * CTT;
    int c   = blockIdx.y * 256 + tid;

    float inv = 1.0f / max_current[0];
    float cb  = -b_act[0] * inv;

    float cur[CTT + 63];
#pragma unroll
    for (int rr = 0; rr < CTT + 63; ++rr) {
        int r = t0 - 63 + rr;
        cur[rr] = (r >= 0) ? currents[(long)r * BATCH + c] : 0.0f;
    }
#pragma unroll
    for (int i = 0; i < CTT; ++i) {
        float acc = 0.0f;
#pragma unroll
        for (int k = 0; k < 64; ++k)
            acc = fmaf(a[k], cur[i + k], acc);
        X[(long)(t0 + i) * BATCH + c] = fmaf(acc, inv, cb);
    }
}

// ---------------------------------------------------------------------------
// Pass 2: serial recurrence, 2 lanes per column (lag-split).
// Lane L: col = blk*32 + (L>>1), h = L&1. tv[m] = (1000/mc)*b_lag[63-m]
// (tap for lag d is tv[d-1]). h handles lags d in [32h+1, 32h+32] via a
// 32-slot phase-renamed ring P[16] (v2f): at step tau (phi = tau mod 32),
// P[phi] holds (h=0) the COMPLETE u for step tau = X_tau + all 64 taps, or
// (h=1) the complete h=1 partial for step tau+32 (its last tap d=33 was
// applied at step tau-1). Per step:
//   uold = P[phi]; hand = dpp0xF5(uold)   (h=0 pulls partner partial)
//   f = dpp0xA0(act(uold))                (true f of the column, both lanes)
//   store f (both lanes, same addr/value)
//   P[phi] = h ? 0 : hand + X_{tau+32}    (rebirth: h=0 slot tau+32 / h=1 slot tau+64)
//   P[(phi+j) mod 32] += tv[32h + j-1]*f, j=1..32  -> 16 v_pk_fma_f32
// Pair alignment alternates with phi parity -> TA (even-aligned) / TB (odd).
// Aligned-pair budget: 48 pairs = 96 VGPR (fits; round-3/4 needed 96 pairs ->
// allocator bloat, ~97 instr/step). 32-phase unrolled body ~8 KB: fits I$
// (round-3/4's 64-phase ~50 KB body overflowed the 32 KiB L1I).
// Init: P = h ? 0 : X_r  (slots 0..31 pre-folded; all pre-history f = 0).
// ---------------------------------------------------------------------------
__global__ __launch_bounds__(64, 1) void rec_kernel(
    const float* X,                       // == out (scratch from pass 1)
    const float* __restrict__ b_lag, const float* __restrict__ poly_coeff,
    const float* __restrict__ max_current, const float* __restrict__ max_firing_rate,
    float* out)
{
    int lane = threadIdx.x;
    int h    = lane & 1;
    int col  = blockIdx.x * 32 + (lane >> 1);

    float inv = 1.0f / max_current[0];
    float g   = 1000.0f * inv;
    int base  = h << 5;                       // this lane's lag-half: m in [base, base+31]

    v2f TA[16], TB[16];
#pragma unroll
    for (int j = 0; j < 16; ++j) {
        // tv(m) = g * b_lag[63 - m]
        TA[j] = (v2f){ g * b_lag[63 - (base + 2*j)], g * b_lag[63 - (base + 2*j + 1)] };
        TB[j] = (v2f){ g * b_lag[63 - (base + ((2*j + 1) & 31))],
                       g * b_lag[63 - (base + ((2*j + 2) & 31))] };
    }

    // tanh(p) = 1 - 2/(exp2(K2*p)+1); K2 = 2*log2(e) folded into squared coeffs.
    const float K2 = 2.8853900817779268f;
    float c0 = poly_coeff[0], c1 = poly_coeff[1], c2 = poly_coeff[2], c3 = poly_coeff[3];
    float k0 = K2*c0*c0, k1 = K2*c1*c1, k2 = K2*c2*c2, k3 = K2*c3*c3;
    float M  = max_firing_rate[0];
    float m2 = -2.0f * M;

    auto act = [&](float u) -> float {
        float u2 = u * u;                       // Estrin, depth 2
        float a1 = fmaf(u, k1, k0);
        float a2 = fmaf(u, k3, k2);
        float p  = fmaf(u2, a2, a1);
        float e  = __builtin_amdgcn_exp2f(p);
        float r_ = __builtin_amdgcn_rcpf(e + 1.0f);
        return fmaxf(fmaf(m2, r_, M), 0.0f);    // relu(M*tanh), overflow-free
    };                                          // h=1 input is bounded (|u|<=~32): safe

    const float* xpc = X   + col;
    float*       opc = out + col;

    v2f P[16];
#pragma unroll
    for (int r = 0; r < 32; ++r) {
        float xv = xpc[r * BATCH];              // both lanes load same addr (cheap)
        P[r >> 1][r & 1] = h ? 0.0f : xv;
    }

    float xc[8], xn[8];
#pragma unroll
    for (int i = 0; i < 8; ++i)                 // X_{tau+32} for phases 0..7 of chunk 0
        xc[i] = xpc[(32 + i) * BATCH];

    // One step at compile-time phase phi. Critical-pair-first tap order: the
    // pair holding slot phi+1 (next step's u on h=0) is updated first.
    auto dostep = [&](int phi, float xreb, int t) {
        float uold = P[phi >> 1][phi & 1];
        float hand = dppf<0xF5>(uold);          // h=0: partner's completed partial
        float f0 = act(uold);
        float f  = dppf<0xA0>(f0);              // column's true f in both lanes
        opc[t * BATCH] = f;                     // same addr+value in both lanes: OK
        P[phi >> 1][phi & 1] = h ? 0.0f : (hand + xreb);
        v2f ff = (v2f){ f, f };
        const int kc = (((phi + 1) & 31) >> 1); // pair containing slot phi+1
        if (phi & 1) {
            const int off = ((phi + 1) >> 1) & 15;   // TA[(k - off) & 15]
#pragma unroll
            for (int kk = 0; kk < 16; ++kk) {
                int k = (kc + kk) & 15;
                P[k] = __builtin_elementwise_fma(TA[(k - off) & 15], ff, P[k]);
            }
        } else {
            const int off = ((phi >> 1) + 1) & 15;   // TB[(k - off) & 15]
#pragma unroll
            for (int kk = 0; kk < 16; ++kk) {
                int k = (kc + kk) & 15;
                P[k] = __builtin_elementwise_fma(TB[(k - off) & 15], ff, P[k]);
            }
        }
    };

    for (int ch = 0; ch < 62; ++ch) {           // 62 full chunks: t = 0..1983
        int t0 = ch * 32;
#pragma unroll
        for (int gph = 0; gph < 4; ++gph) {
            // prefetch next group's X_{t+32} window (consumed 8 steps from now)
            int tf = t0 + (gph + 1) * 8 + 32;
            if (tf + 7 < T_STEPS) {
#pragma unroll
                for (int i = 0; i < 8; ++i) xn[i] = xpc[(tf + i) * BATCH];
            } else {
#pragma unroll
                for (int i = 0; i < 8; ++i)
                    xn[i] = (tf + i < T_STEPS) ? xpc[(tf + i) * BATCH] : 0.0f;
            }
#pragma unroll
            for (int i = 0; i < 8; ++i)
                dostep(gph * 8 + i, xc[i], t0 + gph * 8 + i);
#pragma unroll
            for (int i = 0; i < 8; ++i) xc[i] = xn[i];
        }
    }

    // tail: 16 steps, t = 1984..1999 (rebirth values never read)
#pragma unroll
    for (int phi = 0; phi < 16; ++phi)
        dostep(phi, 0.0f, 1984 + phi);
}

extern "C" void kernel_launch(void* const* d_in, const int* in_sizes, int n_in,
                              void* d_out, int out_size, void* d_ws, size_t ws_size,
                              hipStream_t stream) {
    const float* currents   = (const float*)d_in[0];
    const float* a          = (const float*)d_in[1];
    const float* b_lag      = (const float*)d_in[2];
    const float* poly_coeff = (const float*)d_in[3];
    const float* b_act      = (const float*)d_in[4];
    const float* mc         = (const float*)d_in[5];
    const float* mfr        = (const float*)d_in[6];
    float* out = (float*)d_out;

    // Pass 1: conv + bias + 1/mc folded -> X, staged in `out`.
    conv_kernel<<<dim3(T_STEPS / CTT, BATCH / 256), 256, 0, stream>>>(
        currents, a, b_act, mc, out);
    // Pass 2: lag-split serial recurrence, 32 columns/wave, 64 single-wave blocks.
    rec_kernel<<<BATCH / 32, 64, 0, stream>>>(out, b_lag, poly_coeff, mc, mfr, out);
}

// Round 6
// 261.010 us; speedup vs baseline: 1.2658x; 1.0244x over previous
//
#include <hip/hip_runtime.h>

#define T_STEPS 2000
#define BATCH   2048

typedef float v2f __attribute__((ext_vector_type(2)));

// DPP helper (compile-time ctrl). quad_perm(a,b,c,d): ctrl = a|b<<2|c<<4|d<<6.
// 0x00 = (0,0,0,0): broadcast quad-lane 0.  0xF9 = (1,2,3,3): lane q <- q+1.
template<int CTRL>
__device__ __forceinline__ float dppf(float v) {
    int i = __builtin_bit_cast(int, v);
    return __builtin_bit_cast(float,
        __builtin_amdgcn_update_dpp(i, i, CTRL, 0xf, 0xf, true));
}

// ---------------------------------------------------------------------------
// Single fused kernel. 4 lanes per column (quad), 16 cols/wave, 128 blocks.
// u_t = cb + sum_{d=0..63} inv*a[63-d]*c_{t-d} + sum_{d=1..64} g*b_lag[64-d]*f_{t-d}
// f_t = relu(M * tanh(poly(u_t))),  poly = k0 + k1 u + k2 u^2 + k3 u^3, ki=ci^2.
//
// Ring: 16 slots/lane (8 v2f), phase-renamed: pos = t mod 16. Lane q applies
// BOTH tap families for d in [16q+1, 16q+16] (conv d=64 doesn't exist -> 0 tap;
// conv d=0 applied on-chain: u = fma(a63*inv, c_t, P[phi])). Slot t's partial
// daisy-chains down the quad: born on q3 at step t-64 (value cb), pulled
// q3->q2 @ t-48, q2->q1 @ t-32, q1->q0 @ t-16, read complete on q0 at step t.
// The pull is one quad_perm(1,2,3,3) DPP + cndmask(q3 -> cb) per step; the pk
// taps at position phi happen AFTER the pull, exactly when the reborn/pulled
// slot needs its d = 16q+16 contribution. All hand-offs verified by index
// algebra (see derivation comments at tap setup).
//
// Activation is TRANS-FREE (rounds 0/2/5 all stalled ~190 cyc/step on the
// exp2->rcp dependent chain): tanh(p) ~ p(945+105z+z^2)/(945+420z+15z^2),
// z = p^2 (continued-fraction depth 5, |err| <= 1.1e-3), reciprocal via
// magic-constant + 2 Newton FMA iterations, clamp with v_med3(x, 0, M)
// (negative p -> med3 gives 0 = relu; overflow -> +/-inf -> med3 saturates).
// ---------------------------------------------------------------------------
__global__ __launch_bounds__(64, 1) void fused_kernel(
    const float* __restrict__ currents, const float* __restrict__ a,
    const float* __restrict__ b_lag, const float* __restrict__ poly_coeff,
    const float* __restrict__ b_act, const float* __restrict__ max_current,
    const float* __restrict__ max_firing_rate, float* __restrict__ out)
{
    int lane = threadIdx.x;
    int q    = lane & 3;
    long col = (long)blockIdx.x * 16 + (lane >> 2);

    float inv  = 1.0f / max_current[0];
    float g    = 1000.0f * inv;
    float cb   = -b_act[0] * inv;
    float a63i = a[63] * inv;            // conv lag-0 tap (on-chain fma)

    // Tap windows: lane q covers d in [16q+1, 16q+16]; local j = d-1-16q.
    // fb tap  tv(j) = g * b_lag[64-d] = g * b_lag[63-(16q+j)]
    // conv tap cv(j) = inv * a[63-d],  0 when d > 63 (q3, j=15).
    // At phase phi, ring position pos needs local tap j = (pos-1-phi) mod 16.
    // Pair k = (2k,2k+1): even-aligned j when phi odd -> *A arrays, else *B
    // (odd-start incl. wrap). Same indexing for fb and conv.
    int mb = q << 4;
    v2f FA[8], FB[8], CA[8], CB[8];
#pragma unroll
    for (int j = 0; j < 8; ++j) {
        auto tv = [&](int jl) { return g * b_lag[63 - (mb + jl)]; };
        auto cv = [&](int jl) {
            int d = mb + jl + 1;
            return (d <= 63) ? inv * a[63 - d] : 0.0f;
        };
        FA[j] = (v2f){ tv(2*j),            tv(2*j + 1)          };
        FB[j] = (v2f){ tv((2*j + 1) & 15), tv((2*j + 2) & 15)   };
        CA[j] = (v2f){ cv(2*j),            cv(2*j + 1)          };
        CB[j] = (v2f){ cv((2*j + 1) & 15), cv((2*j + 2) & 15)   };
    }

    // Activation constants. NOTE: no exp2/K2 here — Padé works on p directly.
    float c0 = poly_coeff[0], c1 = poly_coeff[1], c2 = poly_coeff[2], c3 = poly_coeff[3];
    float k0 = c0*c0, k1 = c1*c1, k2 = c2*c2, k3 = c3*c3;
    float M  = max_firing_rate[0];
    float c105M = 105.0f * M, c945M = 945.0f * M;   // M folded into numerator

    bool q3m = (q == 3);

    v2f P[8];
#pragma unroll
    for (int k = 0; k < 8; ++k) P[k] = (v2f){ cb, cb };   // every slot born = cb

    const float* cp = currents + col;
    float*       op = out + col;

    float xc[8], xn[8];
#pragma unroll
    for (int i = 0; i < 8; ++i) xc[i] = cp[(long)i * BATCH];   // c_0..c_7

    auto dostep = [&](int phi, float cval, int t) {
        float uraw = P[phi >> 1][phi & 1];
        float u  = fmaf(a63i, cval, uraw);        // + conv d=0 (chain, c prefetched)
        // p = poly(u), Estrin depth 2
        float u2 = u * u;
        float a1 = fmaf(u, k1, k0);
        float a2 = fmaf(u, k3, k2);
        float p  = fmaf(u2, a2, a1);
        // tanh via CF(5) Padé; z = p^2
        float z  = p * p;
        float z2 = z * z;
        float dn = fmaf(z2, 15.0f, fmaf(z, 420.0f, 945.0f));
        float nm = p * fmaf(z, fmaf(z, M, c105M), c945M);   // M*p*(945+105z+z^2)
        // 1/dn: magic + 2 Newton (pure FMA; dn >= 945, normal, positive)
        float r  = __builtin_bit_cast(float, 0x7EF311C2 - __builtin_bit_cast(int, dn));
        r = r * fmaf(-dn, r, 2.0f);
        r = r * fmaf(-dn, r, 2.0f);
        float f0 = __builtin_amdgcn_fmed3f(nm * r, 0.0f, M);  // relu + clamp
        float f  = dppf<0x00>(f0);                // true f is q0's; broadcast quad
        op[(long)t * BATCH] = f;                  // all 4 lanes: same addr+value
        // daisy pull (pre-read value! d=0 term must not travel): q <- q+1; q3 reborn
        float pulled = dppf<0xF9>(uraw);
        P[phi >> 1][phi & 1] = q3m ? cb : pulled;
        v2f ff  = (v2f){ f, f };
        v2f cc2 = (v2f){ cval, cval };
        const int kc = ((phi + 1) & 15) >> 1;     // pair holding pos phi+1 first
        if (phi & 1) {
            const int off = ((phi + 1) >> 1) & 7;
#pragma unroll
            for (int kk = 0; kk < 8; ++kk) {
                int k = (kc + kk) & 7, idx = (k - off) & 7;
                P[k] = __builtin_elementwise_fma(FA[idx], ff,  P[k]);
                P[k] = __builtin_elementwise_fma(CA[idx], cc2, P[k]);
            }
        } else {
            const int off = ((phi >> 1) + 1) & 7;
#pragma unroll
            for (int kk = 0; kk < 8; ++kk) {
                int k = (kc + kk) & 7, idx = (k - off) & 7;
                P[k] = __builtin_elementwise_fma(FB[idx], ff,  P[k]);
                P[k] = __builtin_elementwise_fma(CB[idx], cc2, P[k]);
            }
        }
    };

    for (int ch = 0; ch < 125; ++ch) {            // 125 * 16 = 2000, no tail
        int t0 = ch * 16;
#pragma unroll
        for (int gph = 0; gph < 2; ++gph) {
            int tf = t0 + (gph + 1) * 8;          // prefetch c for next 8 steps
            if (tf < T_STEPS) {
#pragma unroll
                for (int i = 0; i < 8; ++i) xn[i] = cp[(long)(tf + i) * BATCH];
            } else {
#pragma unroll
                for (int i = 0; i < 8; ++i) xn[i] = 0.0f;   // only tf=2000 hits this
            }
#pragma unroll
            for (int i = 0; i < 8; ++i)
                dostep(gph * 8 + i, xc[i], t0 + gph * 8 + i);
#pragma unroll
            for (int i = 0; i < 8; ++i) xc[i] = xn[i];
        }
    }
}

extern "C" void kernel_launch(void* const* d_in, const int* in_sizes, int n_in,
                              void* d_out, int out_size, void* d_ws, size_t ws_size,
                              hipStream_t stream) {
    const float* currents   = (const float*)d_in[0];
    const float* a          = (const float*)d_in[1];
    const float* b_lag      = (const float*)d_in[2];
    const float* poly_coeff = (const float*)d_in[3];
    const float* b_act      = (const float*)d_in[4];
    const float* mc         = (const float*)d_in[5];
    const float* mfr        = (const float*)d_in[6];
    float* out = (float*)d_out;

    // Single fused kernel: conv + recurrence + activation. 16 cols/block.
    fused_kernel<<<BATCH / 16, 64, 0, stream>>>(
        currents, a, b_lag, poly_coeff, b_act, mc, mfr, out);
}

// Round 7
// 243.980 us; speedup vs baseline: 1.3541x; 1.0698x over previous
//
#include <hip/hip_runtime.h>

#define T_STEPS 2000
#define BATCH   2048

// Round-0 structure (one wave per column, rotating 64-slot ring, verified
// 155 us) + round-6 trans-free activation (verified absmax 1.0 <= 2.0 on this
// data). R0/R2/R5 all stalled ~185-198 cyc/step on the exp2->add->rcp
// dependent chain (~125 cyc); the Pade + magic-Newton chain is ~40 cyc of
// pure 4-cyc FMAs. Issue stays ~17 instr/step/wave, 2048 waves = 8/CU.
//
// Ring invariant (entering global step t): lane L holds
//   R_L = cba + sum_{tau<=t-1} (a[63-(t+L-tau)]/mc) * c_tau        (conv part)
//       +       gamma-weighted feedback from f_{tau<=t-1}
// Per step t:
//   1. R += af * c_t          af[L] = a[63-L]/mc   (lane 0 now = u_t complete)
//   2. u = readlane(R, 0);  f_t = relu(M * tanh_pade(poly(u)))
//   3. rotate R left one lane (DPP wave_rol:1), lane 63 <- cba
//   4. R += gam * f_t         gam[L] = (1000/mc) * b_lag[63-L]
// Rotate/cndmask depend on R (not f) -> they overlap the activation chain.
__global__ __launch_bounds__(256) void fused_kernel(
    const float* __restrict__ currents, const float* __restrict__ a,
    const float* __restrict__ b_lag, const float* __restrict__ poly_coeff,
    const float* __restrict__ b_act, const float* __restrict__ max_current,
    const float* __restrict__ max_firing_rate, float* __restrict__ out)
{
    int tid  = threadIdx.x;
    int lane = tid & 63;
    int wid  = tid >> 6;
    int b    = blockIdx.x * 4 + wid;

    float inv = 1.0f / max_current[0];
    float cba = -b_act[0] * inv;
    float af  = a[63 - lane] * inv;                 // fixed per-lane conv tap
    float gam = (1000.0f * inv) * b_lag[63 - lane]; // fixed per-lane feedback tap

    // Trans-free activation (verbatim from round 6, hardware-verified):
    // tanh(p) ~ p*(945+105z+z^2)/(945+420z+15z^2), z=p^2 (CF depth 5,
    // |err|<=1.1e-3); reciprocal via magic-constant + 2 Newton FMA steps
    // (dn >= 945: normal, positive); relu+clamp via v_med3.
    float c0 = poly_coeff[0], c1 = poly_coeff[1], c2 = poly_coeff[2], c3 = poly_coeff[3];
    float k0 = c0*c0, k1 = c1*c1, k2 = c2*c2, k3 = c3*c3;
    float M  = max_firing_rate[0];
    float c105M = 105.0f * M, c945M = 945.0f * M;   // M folded into numerator

    auto bcast = [](float v, int l) {
        return __builtin_bit_cast(float,
            __builtin_amdgcn_readlane(__builtin_bit_cast(int, v), l));
    };
    auto rotl1 = [](float v) {   // dst[L] = src[(L+1) & 63]  (wave_rol:1)
        int i = __builtin_bit_cast(int, v);
        return __builtin_bit_cast(float,
            __builtin_amdgcn_update_dpp(i, i, 0x134, 0xf, 0xf, false));
    };

    const float* ccol   = currents + b;
    float*       outcol = out + b;

    float R  = cba;                          // all slots born with the bias
    float cv = ccol[(long)lane * BATCH];     // c[lane] for chunk 0
    float fv = 0.0f;

    auto step = [&](int s) {
        float c = bcast(cv, s);                       // c_t (wave-uniform)
        R = fmaf(af, c, R);                           // complete lane 0 -> u_t
        float u = bcast(R, 0);
        float u2 = u * u;                             // poly: Estrin, depth 2
        float a1 = fmaf(u, k1, k0);
        float a2 = fmaf(u, k3, k2);
        float p  = fmaf(u2, a2, a1);
        float z  = p * p;                             // Pade tanh
        float z2 = z * z;
        float dn = fmaf(z2, 15.0f, fmaf(z, 420.0f, 945.0f));
        float nm = p * fmaf(z, fmaf(z, M, c105M), c945M);   // M*p*(945+105z+z^2)
        float r  = __builtin_bit_cast(float,
                       0x7EF311C2 - __builtin_bit_cast(int, dn));
        r = r * fmaf(-dn, r, 2.0f);                   // Newton 1
        r = r * fmaf(-dn, r, 2.0f);                   // Newton 2
        float f  = __builtin_amdgcn_fmed3f(nm * r, 0.0f, M);  // relu + clamp
        float Rr = rotl1(R);                          // overlaps activation
        Rr = (lane == 63) ? cba : Rr;                 // fresh slot for t+64
        R  = fmaf(gam, f, Rr);
        fv = (lane == s) ? f : fv;                    // stash f[t0+s] in lane s
    };

    // 31 full chunks of 64 steps (t = 0 .. 1983)
    for (int chunk = 0; chunk < 31; ++chunk) {
        int t0 = chunk * 64;
        int tp = t0 + 64 + lane;                      // prefetch next chunk's currents
        float cv_next = (tp < T_STEPS) ? ccol[(long)tp * BATCH] : 0.0f;
#pragma unroll
        for (int s = 0; s < 64; ++s) step(s);
        outcol[(long)(t0 + lane) * BATCH] = fv;
        cv = cv_next;
    }
    // tail: 16 steps (t = 1984 .. 1999)
#pragma unroll
    for (int s = 0; s < 16; ++s) step(s);
    if (lane < 16) outcol[(long)(1984 + lane) * BATCH] = fv;
}

extern "C" void kernel_launch(void* const* d_in, const int* in_sizes, int n_in,
                              void* d_out, int out_size, void* d_ws, size_t ws_size,
                              hipStream_t stream) {
    const float* currents   = (const float*)d_in[0];
    const float* a          = (const float*)d_in[1];
    const float* b_lag      = (const float*)d_in[2];
    const float* poly_coeff = (const float*)d_in[3];
    const float* b_act      = (const float*)d_in[4];
    const float* mc         = (const float*)d_in[5];
    const float* mfr        = (const float*)d_in[6];
    float* out = (float*)d_out;

    fused_kernel<<<BATCH / 4, 256, 0, stream>>>(
        currents, a, b_lag, poly_coeff, b_act, mc, mfr, out);
}

// Round 8
// 219.586 us; speedup vs baseline: 1.5046x; 1.1111x over previous
//
#include <hip/hip_runtime.h>

#define T_STEPS 2000
#define BATCH   2048

// wave_rol:1 (0x134): dst[L] = src[(L+1) & 63] — hardware-verified in round 0.
__device__ __forceinline__ float rol1(float v) {
    int i = __builtin_bit_cast(int, v);
    return __builtin_bit_cast(float,
        __builtin_amdgcn_update_dpp(i, i, 0x134, 0xf, 0xf, false));
}
// ds_swizzle BitMode offset=0: src_lane = ((i&0)|0)^0 = 0 per 32-lane half ->
// lanes 0-31 get lane 0's value, lanes 32-63 get lane 32's. Pure crossbar
// (no LDS storage), lgkmcnt-counted; issued one full step before use.
__device__ __forceinline__ float bcast0(float v) {
    return __builtin_bit_cast(float,
        __builtin_amdgcn_ds_swizzle(__builtin_bit_cast(int, v), 0x0000));
}

// ---------------------------------------------------------------------------
// Single fused kernel. 2 columns per wave (32 lanes each), 1024 waves = one
// per SIMD. Ring invariant: entering step t, slot k (k=0..63) holds
//   P_t(k) = cba + sum_{i=k+1..63} af_i c_{t-(i-k)} + sum_{i=k+1..64} gam_i f_{t-(i-k)}
// with af_i = a[63-i]/mc (af_64=0), gam_i = (1000/mc) b_lag[64-i].
// Update: P_{t+1}(k) = P_t(k+1) + af_{k+1} c_t + gam_{k+1} f_t; P_{t+1}(63) =
// cba + gam_64 f_t.  u_t = P_t(0) + af_0 c_t.
//
// Storage: k = 2r + j (r = lane&31, j = plane 0/1), planes phase-renamed
// between regs A,B each step (even step: A=plane0,B=plane1; odd: swapped).
// Per step: plane1 -> new plane0 in place (+taps af_{2r+1}, gam_{2r+1});
// plane0 -> new plane1 via wave_rol:1 + newborn cndmask(r==31 -> cba)
// (+taps af_{2r+2}, gam_{2r+2}; r=31 gives af_64=0, gam_64 ✓). The rol wrap
// contaminates only r==31 lanes, which the newborn cndmask overwrites.
//
// CHAIN DECOUPLING (the round-8 point): u_t = P_{t-1}(1) + af_1 c_{t-1}
// + af_0 c_t + gam_1 f_{t-1}. P_{t-1}(1) = plane1(r=0) at the START of step
// t-1 -> ds_swizzle-broadcast it then, consume it at step t. The activation
// runs redundantly on all 32 lanes of the group, so f_t is born broadcast:
// NO readlane, NO DPP, NO swizzle anywhere in the serial dependence chain —
// it is one fma + pure-FMA Pade activation (verified absmax 1.0 in R6/R7).
// Rounds 0/2/5/7 all stalled 186-246 cyc/step with cross-lane ops on-chain.
// ---------------------------------------------------------------------------
__global__ __launch_bounds__(256, 1) void fused_kernel(
    const float* __restrict__ currents, const float* __restrict__ a,
    const float* __restrict__ b_lag, const float* __restrict__ poly_coeff,
    const float* __restrict__ b_act, const float* __restrict__ max_current,
    const float* __restrict__ max_firing_rate, float* __restrict__ out)
{
    int tid  = threadIdx.x;
    int r    = tid & 31;
    long col = (long)blockIdx.x * 8 + (tid >> 5);

    float inv = 1.0f / max_current[0];
    float g   = 1000.0f * inv;
    float cba = -b_act[0] * inv;

    // scalar taps for the u-reconstruction
    float af0  = a[63] * inv;                    // af_0
    float af1  = a[62] * inv;                    // af_1
    float gam1 = g * b_lag[63];                  // gam_1
    // per-lane ring taps
    float AFe  = a[63 - (2*r + 1)] * inv;        // af_{2r+1}  (2r+1 <= 63)
    float GAMe = g * b_lag[64 - (2*r + 1)];      // gam_{2r+1}
    float AFo  = (r < 31) ? a[63 - (2*r + 2)] * inv : 0.0f;  // af_{2r+2}, af_64=0
    float GAMo = g * b_lag[64 - (2*r + 2)];      // gam_{2r+2}; r=31 -> b_lag[0]=gam_64

    // trans-free activation (verbatim R6/R7, verified absmax 1.0 <= 2.0):
    // tanh(p) ~ p(945+105z+z^2)/(945+420z+15z^2), z=p^2; rcp via magic+2 Newton.
    float c0 = poly_coeff[0], c1 = poly_coeff[1], c2 = poly_coeff[2], c3 = poly_coeff[3];
    float k0 = c0*c0, k1 = c1*c1, k2 = c2*c2, k3 = c3*c3;
    float M  = max_firing_rate[0];
    float c105M = 105.0f * M, c945M = 945.0f * M;

    bool nb = (r == 31);                         // newborn lane mask

    const float* cp = currents + col;
    float*       op = out + col;

    float A = cba, B = cba;                      // ring planes (all slots = cba)
    float bc = cba;                              // P_{-1}(1) equivalent
    float f  = 0.0f, cprev = 0.0f, fv = 0.0f;

    float xc[8], xn[8];
#pragma unroll
    for (int i = 0; i < 8; ++i) xc[i] = cp[(long)i * BATCH];

    // One step; par = t&1, s = step-in-chunk (0..31), c = c_t. All compile-time
    // branches. Swizzle of plane1 issued FIRST (pre-update value), consumed
    // next step — its latency hides under this step's activation.
    auto STEP = [&](int par, int s, float c) {
        float bcn = bcast0(par ? A : B);          // P_t(1) -> for u_{t+1}
        float u = fmaf(af1, cprev, bc);           // off-chain (bc ready)
        u = fmaf(af0, c, u);
        u = fmaf(gam1, f, u);                     // ONLY f-dependent op pre-act
        float u2 = u * u;                         // Estrin poly
        float a1 = fmaf(u, k1, k0);
        float a2 = fmaf(u, k3, k2);
        float p  = fmaf(u2, a2, a1);
        float z  = p * p;                         // Pade tanh
        float z2 = z * z;
        float dn = fmaf(z2, 15.0f, fmaf(z, 420.0f, 945.0f));
        float nm = p * fmaf(z, fmaf(z, M, c105M), c945M);
        float rc = __builtin_bit_cast(float,
                       0x7EF311C2 - __builtin_bit_cast(int, dn));
        rc = rc * fmaf(-dn, rc, 2.0f);
        rc = rc * fmaf(-dn, rc, 2.0f);
        float fn = __builtin_amdgcn_fmed3f(nm * rc, 0.0f, M);  // relu+clamp
        fv = (r == s) ? fn : fv;                  // stash (off-chain)
        // ring update (off-chain): shifted reg = old plane0 -> new plane1
        float sh = rol1(par ? B : A);
        sh = nb ? cba : sh;                       // newborn slot k=63
        sh = fmaf(AFo, c, sh);
        sh = fmaf(GAMo, fn, sh);
        // no-shift reg = old plane1 -> new plane0
        float ns = fmaf(AFe, c, par ? A : B);
        ns = fmaf(GAMe, fn, ns);
        if (par) { B = sh; A = ns; } else { A = sh; B = ns; }
        f = fn; cprev = c; bc = bcn;
    };

    for (int ch = 0; ch < 62; ++ch) {            // 62 full chunks: t = 0..1983
        int t0 = ch * 32;
#pragma unroll
        for (int gg = 0; gg < 4; ++gg) {
            int tf = t0 + gg * 8 + 8;            // prefetch next group's c
#pragma unroll
            for (int i = 0; i < 8; ++i)          // max addr: 1952+24+8+7 = 1991 ✓
                xn[i] = cp[(long)(tf + i) * BATCH];
#pragma unroll
            for (int i = 0; i < 8; ++i)
                STEP((gg * 8 + i) & 1, gg * 8 + i, xc[i]);
#pragma unroll
            for (int i = 0; i < 8; ++i) xc[i] = xn[i];
        }
        op[(long)(t0 + r) * BATCH] = fv;         // lane r holds f[t0+r]
    }
    // tail: 16 steps, t = 1984..1999 (xc holds c[1984..1991] from ch=61 g3)
#pragma unroll
    for (int gg = 0; gg < 2; ++gg) {
        int tf = 1984 + gg * 8 + 8;
#pragma unroll
        for (int i = 0; i < 8; ++i)
            xn[i] = (tf + i < T_STEPS) ? cp[(long)(tf + i) * BATCH] : 0.0f;
#pragma unroll
        for (int i = 0; i < 8; ++i)
            STEP((gg * 8 + i) & 1, gg * 8 + i, xc[i]);
#pragma unroll
        for (int i = 0; i < 8; ++i) xc[i] = xn[i];
    }
    if (r < 16) op[(long)(1984 + r) * BATCH] = fv;
}

extern "C" void kernel_launch(void* const* d_in, const int* in_sizes, int n_in,
                              void* d_out, int out_size, void* d_ws, size_t ws_size,
                              hipStream_t stream) {
    const float* currents   = (const float*)d_in[0];
    const float* a          = (const float*)d_in[1];
    const float* b_lag      = (const float*)d_in[2];
    const float* poly_coeff = (const float*)d_in[3];
    const float* b_act      = (const float*)d_in[4];
    const float* mc         = (const float*)d_in[5];
    const float* mfr        = (const float*)d_in[6];
    float* out = (float*)d_out;

    // 256 blocks x 256 threads = 1024 waves (1/SIMD), 2 columns per wave.
    fused_kernel<<<BATCH / 8, 256, 0, stream>>>(
        currents, a, b_lag, poly_coeff, b_act, mc, mfr, out);
}